// Round 1
// baseline (248.521 us; speedup 1.0000x reference)
//
#include <hip/hip_runtime.h>
#include <stdint.h>
#include <stddef.h>

// Problem constants
#define BB 8
#define CC 16
#define DD 192
#define OCC 4
#define OHH 50
#define OWW 200

#define LDP 200   // padded LDS row stride in bf16 elements (192 + 8)
#define CH  24    // 8-element chunks per 192 row

typedef __attribute__((ext_vector_type(8))) short s8v;   // 8 bf16 = 16B (MFMA A/B frag)
typedef __attribute__((ext_vector_type(4))) short s4v;   // 4 bf16 = 8B
typedef __attribute__((ext_vector_type(4))) float f4v;   // 4 fp32
typedef __attribute__((ext_vector_type(4))) float f32x4; // MFMA C/D frag

__device__ __forceinline__ short rne_bf16(float f) {
  uint32_t u = __float_as_uint(f);
  u += 0x7fffu + ((u >> 16) & 1u);
  return (short)(u >> 16);
}
__device__ __forceinline__ float bf2f(short s) {
  return __uint_as_float(((uint32_t)(uint16_t)s) << 16);
}

// ---------------- prep kernels ----------------

__global__ void cvt_bf16(const float* __restrict__ s, short* __restrict__ d, int n4) {
  int idx = blockIdx.x * 256 + threadIdx.x;
  if (idx >= n4) return;
  f4v v = *(const f4v*)(s + (size_t)idx * 4);
  s4v o;
  #pragma unroll
  for (int r = 0; r < 4; ++r) o[r] = rne_bf16(v[r]);
  *(s4v*)(d + (size_t)idx * 4) = o;
}

// XTb[outer][q][p] = x[outer][p][q], 192x192, bf16 out
__global__ void transpose_x(const float* __restrict__ x, short* __restrict__ XTb) {
  __shared__ float tile[32][33];
  int outer = blockIdx.z;
  int p0 = blockIdx.x * 32, q0 = blockIdx.y * 32;
  int tx = threadIdx.x, ty = threadIdx.y;
  const float* src = x + (size_t)outer * DD * DD;
  for (int r = ty; r < 32; r += 8)
    tile[r][tx] = src[(size_t)(p0 + r) * DD + q0 + tx];
  __syncthreads();
  short* dst = XTb + (size_t)outer * DD * DD;
  for (int r = ty; r < 32; r += 8)
    dst[(size_t)(q0 + r) * DD + p0 + tx] = rne_bf16(tile[tx][r]);
}

// PTTb[outer][n][q] = PT[outer][q][n], PT is 192x200, out 200x192, bf16
__global__ void transpose_pt(const float* __restrict__ PT, short* __restrict__ PTTb) {
  __shared__ float tile[32][33];
  int outer = blockIdx.z;
  int q0 = blockIdx.x * 32, n0 = blockIdx.y * 32;
  int tx = threadIdx.x, ty = threadIdx.y;
  const float* src = PT + (size_t)outer * DD * OWW;
  for (int r = ty; r < 32; r += 8)
    tile[r][tx] = (n0 + tx < OWW) ? src[(size_t)(q0 + r) * OWW + n0 + tx] : 0.f;
  __syncthreads();
  short* dst = PTTb + (size_t)outer * OWW * DD;
  for (int r = ty; r < 32; r += 8)
    if (n0 + r < OWW) dst[(size_t)(n0 + r) * DD + q0 + tx] = rne_bf16(tile[tx][r]);
}

// ---------------- stage A ----------------
// y[b,i] = sum_j R[i,j] @ x[b,j] @ R[i,j]^T, split over jg halves.
// Block = (b, i, jg), 512 threads (8 waves as 2x4: wq covers 6 row-tiles, wm covers 3 col-tiles).
// mm1: T^T[q][m] = sum_p XT[q][p] R[m][p]   (A = XT rows, B = R rows)
// pack T row-major [m][q] via ds_write_b64 (C-layout gives 4 consecutive q per lane)
// mm2: y^T[n][m] += sum_q R[n][q] T[m][q]   (A = R rows, B = T rows)
// final pack -> y natural [p][q], coalesced bf16 store.
__global__ __launch_bounds__(512, 2) void stageA(const short* __restrict__ Rb,
                                                 const short* __restrict__ XTb,
                                                 short* __restrict__ ypart) {
  __shared__ __align__(16) short ldsR[DD * LDP];
  __shared__ __align__(16) short lds2[DD * LDP];
  const int tid = threadIdx.x;
  const int bx = blockIdx.x;
  const int b = bx >> 5, i = (bx >> 1) & 15, jg = bx & 1;
  const int lane15 = tid & 15, quad = (tid & 63) >> 4;
  const int wid = tid >> 6;
  const int wm = wid & 3;   // 0..3 -> 3 m-tiles each (12 total)
  const int wq = wid >> 2;  // 0..1 -> 6 q/n-tiles each (12 total)

  f32x4 acc_y[6][3];
  #pragma unroll
  for (int a = 0; a < 6; ++a)
    #pragma unroll
    for (int c = 0; c < 3; ++c) acc_y[a][c] = (f32x4){0.f, 0.f, 0.f, 0.f};

  for (int jj = 0; jj < 8; ++jj) {
    const int j = jg * 8 + jj;
    __syncthreads();  // previous iter done reading ldsR/lds2
    {
      const short* srcR = Rb + (size_t)(i * CC + j) * (DD * DD);
      const short* srcX = XTb + (size_t)(b * CC + j) * (DD * DD);
      for (int c = tid; c < DD * CH; c += 512) {
        int row = c / CH, col = c % CH;
        *(s8v*)(&ldsR[row * LDP + col * 8]) = *(const s8v*)(srcR + (size_t)c * 8);
        *(s8v*)(&lds2[row * LDP + col * 8]) = *(const s8v*)(srcX + (size_t)c * 8);
      }
    }
    __syncthreads();

    // mm1: T^T
    f32x4 acc_t[6][3];
    #pragma unroll
    for (int a = 0; a < 6; ++a)
      #pragma unroll
      for (int c = 0; c < 3; ++c) acc_t[a][c] = (f32x4){0.f, 0.f, 0.f, 0.f};

    #pragma unroll
    for (int kc = 0; kc < 6; ++kc) {
      s8v af[6], bf[3];
      #pragma unroll
      for (int a = 0; a < 6; ++a)
        af[a] = *(const s8v*)(&lds2[((wq * 6 + a) * 16 + lane15) * LDP + kc * 32 + quad * 8]);
      #pragma unroll
      for (int c = 0; c < 3; ++c)
        bf[c] = *(const s8v*)(&ldsR[((wm * 3 + c) * 16 + lane15) * LDP + kc * 32 + quad * 8]);
      #pragma unroll
      for (int a = 0; a < 6; ++a)
        #pragma unroll
        for (int c = 0; c < 3; ++c)
          acc_t[a][c] = __builtin_amdgcn_mfma_f32_16x16x32_bf16(af[a], bf[c], acc_t[a][c], 0, 0, 0);
    }
    __syncthreads();  // done reading XT in lds2; overwrite with T

    // pack T[m][q] (bf16) into lds2
    #pragma unroll
    for (int a = 0; a < 6; ++a) {
      #pragma unroll
      for (int c = 0; c < 3; ++c) {
        s4v pk;
        #pragma unroll
        for (int r = 0; r < 4; ++r) pk[r] = rne_bf16(acc_t[a][c][r]);
        int m = (wm * 3 + c) * 16 + lane15;
        int q0 = (wq * 6 + a) * 16 + quad * 4;
        *(s4v*)(&lds2[m * LDP + q0]) = pk;
      }
    }
    __syncthreads();

    // mm2: y^T += R rows x T rows
    #pragma unroll
    for (int kc = 0; kc < 6; ++kc) {
      s8v af[6], bf[3];
      #pragma unroll
      for (int a = 0; a < 6; ++a)
        af[a] = *(const s8v*)(&ldsR[((wq * 6 + a) * 16 + lane15) * LDP + kc * 32 + quad * 8]);
      #pragma unroll
      for (int c = 0; c < 3; ++c)
        bf[c] = *(const s8v*)(&lds2[((wm * 3 + c) * 16 + lane15) * LDP + kc * 32 + quad * 8]);
      #pragma unroll
      for (int a = 0; a < 6; ++a)
        #pragma unroll
        for (int c = 0; c < 3; ++c)
          acc_y[a][c] = __builtin_amdgcn_mfma_f32_16x16x32_bf16(af[a], bf[c], acc_y[a][c], 0, 0, 0);
    }
  }

  // pack y natural [p][q] into lds2, then coalesced store
  __syncthreads();
  #pragma unroll
  for (int a = 0; a < 6; ++a) {
    #pragma unroll
    for (int c = 0; c < 3; ++c) {
      s4v pk;
      #pragma unroll
      for (int r = 0; r < 4; ++r) pk[r] = rne_bf16(acc_y[a][c][r]);
      int p = (wm * 3 + c) * 16 + lane15;       // y row (= m)
      int q0 = (wq * 6 + a) * 16 + quad * 4;    // y col (= n), 4 consecutive
      *(s4v*)(&lds2[p * LDP + q0]) = pk;
    }
  }
  __syncthreads();
  {
    short* dst = ypart + (size_t)(jg * (BB * CC) + b * CC + i) * (DD * DD);
    for (int c = tid; c < DD * CH; c += 512) {
      int row = c / CH, col = c % CH;
      *(s8v*)(dst + (size_t)c * 8) = *(const s8v*)(&lds2[row * LDP + col * 8]);
    }
  }
}

// ---------------- stage B1 ----------------
// V[b,i,j][n][p] (= V^T, bf16) where V = y[b,j] @ PT[i,j]  (k = q)
// Block = (b,i,j), 512 threads. A = y rows (natural layout), B = PT^T rows.
__global__ __launch_bounds__(512, 2) void stageB1(const short* __restrict__ ypart,
                                                  const short* __restrict__ PTTb,
                                                  short* __restrict__ V) {
  __shared__ __align__(16) short ldsY[DD * LDP];    // y[p][q]
  __shared__ __align__(16) short ldsPT[208 * LDP];  // PT^T[n][q], rows 200..207 zero
  const int tid = threadIdx.x;
  const int bx = blockIdx.x;
  const int b = bx >> 6, i = (bx >> 4) & 3, j = bx & 15;
  const int lane15 = tid & 15, quad = (tid & 63) >> 4;
  const int wid = tid >> 6;
  const int wp = wid >> 1;  // 0..3 -> 3 p-tiles each
  const int wn = wid & 1;   // 0..1 -> 7 / 6 n-tiles

  {
    const short* p0 = ypart + (size_t)(b * CC + j) * (DD * DD);
    const short* p1 = p0 + (size_t)(BB * CC) * (DD * DD);
    for (int c = tid; c < DD * CH; c += 512) {
      s8v v0 = *(const s8v*)(p0 + (size_t)c * 8);
      s8v v1 = *(const s8v*)(p1 + (size_t)c * 8);
      s8v o;
      #pragma unroll
      for (int r = 0; r < 8; ++r) o[r] = rne_bf16(bf2f(v0[r]) + bf2f(v1[r]));
      int row = c / CH, col = c % CH;
      *(s8v*)(&ldsY[row * LDP + col * 8]) = o;
    }
    const short* pt = PTTb + (size_t)(i * CC + j) * (OWW * DD);
    s8v z = {0, 0, 0, 0, 0, 0, 0, 0};
    for (int c = tid; c < 208 * CH; c += 512) {
      s8v v = (c < OWW * CH) ? *(const s8v*)(pt + (size_t)c * 8) : z;
      int row = c / CH, col = c % CH;
      *(s8v*)(&ldsPT[row * LDP + col * 8]) = v;
    }
  }
  __syncthreads();

  f32x4 acc[3][7];
  #pragma unroll
  for (int a = 0; a < 3; ++a)
    #pragma unroll
    for (int e = 0; e < 7; ++e) acc[a][e] = (f32x4){0.f, 0.f, 0.f, 0.f};

  #pragma unroll
  for (int kc = 0; kc < 6; ++kc) {
    s8v af[3], bf[7];
    #pragma unroll
    for (int a = 0; a < 3; ++a)
      af[a] = *(const s8v*)(&ldsY[((wp * 3 + a) * 16 + lane15) * LDP + kc * 32 + quad * 8]);
    #pragma unroll
    for (int e = 0; e < 7; ++e) {
      int tn = wn * 7 + e;
      if (tn < 13)
        bf[e] = *(const s8v*)(&ldsPT[(tn * 16 + lane15) * LDP + kc * 32 + quad * 8]);
    }
    #pragma unroll
    for (int a = 0; a < 3; ++a)
      #pragma unroll
      for (int e = 0; e < 7; ++e)
        if (wn * 7 + e < 13)
          acc[a][e] = __builtin_amdgcn_mfma_f32_16x16x32_bf16(af[a], bf[e], acc[a][e], 0, 0, 0);
  }

  // store V^T[n][p] (bf16), b64 packs of 4 consecutive p
  short* vb = V + (size_t)bx * (OWW * DD);
  #pragma unroll
  for (int a = 0; a < 3; ++a) {
    #pragma unroll
    for (int e = 0; e < 7; ++e) {
      int tn = wn * 7 + e;
      if (tn < 13) {
        int n = tn * 16 + lane15;
        if (n < OWW) {
          s4v pk;
          #pragma unroll
          for (int r = 0; r < 4; ++r) pk[r] = rne_bf16(acc[a][e][r]);
          int p0 = (wp * 3 + a) * 16 + quad * 4;
          *(s4v*)(vb + (size_t)n * DD + p0) = pk;
        }
      }
    }
  }
}

// ---------------- stage B2 ----------------
// out[b,i][m][n] = sum_j P[i,j] @ V[b,i,j]   (k = p, 192)
// Block = (b, i, n-quarter of 50), 256 threads (4 waves as 2x2).
__global__ __launch_bounds__(256, 4) void stageB2(const short* __restrict__ Pb,
                                                  const short* __restrict__ V,
                                                  float* __restrict__ out) {
  __shared__ __align__(16) short ldsP[64 * LDP];
  __shared__ __align__(16) short ldsV[64 * LDP];
  const int tid = threadIdx.x;
  const int bx = blockIdx.x;
  const int b = bx >> 4, i = (bx >> 2) & 3, nq = bx & 3;
  const int lane15 = tid & 15, quad = (tid & 63) >> 4;
  const int wid = tid >> 6;
  const int wm = wid >> 1, wn = wid & 1;

  f32x4 acc[2][2];
  #pragma unroll
  for (int a = 0; a < 2; ++a)
    #pragma unroll
    for (int e = 0; e < 2; ++e) acc[a][e] = (f32x4){0.f, 0.f, 0.f, 0.f};

  s8v z = {0, 0, 0, 0, 0, 0, 0, 0};
  for (int j = 0; j < CC; ++j) {
    __syncthreads();
    const short* ps = Pb + (size_t)(i * CC + j) * (OHH * DD);
    const short* vs = V + (size_t)((b * OCC + i) * CC + j) * (OWW * DD) + (size_t)nq * 50 * DD;
    for (int c = tid; c < 64 * CH; c += 256) {
      int row = c / CH, col = c % CH;
      s8v vp = (c < 50 * CH) ? *(const s8v*)(ps + (size_t)c * 8) : z;
      s8v vv = (c < 50 * CH) ? *(const s8v*)(vs + (size_t)c * 8) : z;
      *(s8v*)(&ldsP[row * LDP + col * 8]) = vp;
      *(s8v*)(&ldsV[row * LDP + col * 8]) = vv;
    }
    __syncthreads();
    #pragma unroll
    for (int kc = 0; kc < 6; ++kc) {
      s8v af[2], bf[2];
      #pragma unroll
      for (int a = 0; a < 2; ++a)
        af[a] = *(const s8v*)(&ldsP[((wm * 2 + a) * 16 + lane15) * LDP + kc * 32 + quad * 8]);
      #pragma unroll
      for (int e = 0; e < 2; ++e)
        bf[e] = *(const s8v*)(&ldsV[((wn * 2 + e) * 16 + lane15) * LDP + kc * 32 + quad * 8]);
      #pragma unroll
      for (int a = 0; a < 2; ++a)
        #pragma unroll
        for (int e = 0; e < 2; ++e)
          acc[a][e] = __builtin_amdgcn_mfma_f32_16x16x32_bf16(af[a], bf[e], acc[a][e], 0, 0, 0);
    }
  }

  #pragma unroll
  for (int a = 0; a < 2; ++a) {
    #pragma unroll
    for (int e = 0; e < 2; ++e) {
      #pragma unroll
      for (int r = 0; r < 4; ++r) {
        int m = (wm * 2 + a) * 16 + quad * 4 + r;
        int cl = (wn * 2 + e) * 16 + lane15;
        if (m < OHH && cl < 50)
          out[((size_t)(b * OCC + i) * OHH + m) * OWW + nq * 50 + cl] = acc[a][e][r];
      }
    }
  }
}

// ---------------- launcher ----------------

extern "C" void kernel_launch(void* const* d_in, const int* in_sizes, int n_in,
                              void* d_out, int out_size, void* d_ws, size_t ws_size,
                              hipStream_t stream) {
  const float* x  = (const float*)d_in[0];
  const float* R  = (const float*)d_in[1];
  const float* P  = (const float*)d_in[2];
  const float* PT = (const float*)d_in[3];
  float* out = (float*)d_out;

  short* W = (short*)d_ws;
  const size_t nR   = (size_t)CC * CC * DD * DD;     // 9,437,184
  const size_t nX   = (size_t)BB * CC * DD * DD;     // 4,718,592
  const size_t nP   = (size_t)OCC * CC * OHH * DD;   // 614,400
  const size_t nPT  = (size_t)OCC * CC * OWW * DD;   // 2,457,600
  const size_t nYP  = 2 * nX;                        // 9,437,184
  short* Rb    = W;
  short* XTb   = Rb + nR;
  short* Pb    = XTb + nX;
  short* PTTb  = Pb + nP;
  short* ypart = PTTb + nPT;
  short* Vws   = ypart + nYP;

  cvt_bf16<<<(int)(nR / 4 / 256), 256, 0, stream>>>(R, Rb, (int)(nR / 4));
  cvt_bf16<<<(int)(nP / 4 / 256), 256, 0, stream>>>(P, Pb, (int)(nP / 4));
  transpose_x<<<dim3(6, 6, BB * CC), dim3(32, 8), 0, stream>>>(x, XTb);
  transpose_pt<<<dim3(6, 7, OCC * CC), dim3(32, 8), 0, stream>>>(PT, PTTb);

  stageA<<<BB * CC * 2, 512, 0, stream>>>(Rb, XTb, ypart);
  stageB1<<<BB * OCC * CC, 512, 0, stream>>>(ypart, PTTb, Vws);
  stageB2<<<BB * OCC * 4, 256, 0, stream>>>(Pb, Vws, out);
}

// Round 2
// 216.856 us; speedup vs baseline: 1.1460x; 1.1460x over previous
//
#include <hip/hip_runtime.h>
#include <stdint.h>
#include <stddef.h>

// Problem constants
#define BB 8
#define CC 16
#define DD 192
#define OCC 4
#define OHH 50
#define OWW 200

#define LDP 200   // padded LDS row stride in bf16 elements (192 + 8)
#define CH  24    // 8-element chunks per 192 row

typedef __attribute__((ext_vector_type(8))) short s8v;   // 8 bf16 = 16B (MFMA A/B frag)
typedef __attribute__((ext_vector_type(4))) short s4v;   // 4 bf16 = 8B
typedef __attribute__((ext_vector_type(4))) float f4v;   // 4 fp32
typedef __attribute__((ext_vector_type(4))) float f32x4; // MFMA C/D frag

__device__ __forceinline__ short rne_bf16(float f) {
  uint32_t u = __float_as_uint(f);
  u += 0x7fffu + ((u >> 16) & 1u);
  return (short)(u >> 16);
}
__device__ __forceinline__ float bf2f(short s) {
  return __uint_as_float(((uint32_t)(uint16_t)s) << 16);
}

// ---------------- prep kernels ----------------

__global__ void cvt_bf16(const float* __restrict__ s, short* __restrict__ d, int n4) {
  int idx = blockIdx.x * 256 + threadIdx.x;
  if (idx >= n4) return;
  f4v v = *(const f4v*)(s + (size_t)idx * 4);
  s4v o;
  #pragma unroll
  for (int r = 0; r < 4; ++r) o[r] = rne_bf16(v[r]);
  *(s4v*)(d + (size_t)idx * 4) = o;
}

// XTb[outer][q][p] = x[outer][p][q], 192x192, bf16 out
__global__ void transpose_x(const float* __restrict__ x, short* __restrict__ XTb) {
  __shared__ float tile[32][33];
  int outer = blockIdx.z;
  int p0 = blockIdx.x * 32, q0 = blockIdx.y * 32;
  int tx = threadIdx.x, ty = threadIdx.y;
  const float* src = x + (size_t)outer * DD * DD;
  for (int r = ty; r < 32; r += 8)
    tile[r][tx] = src[(size_t)(p0 + r) * DD + q0 + tx];
  __syncthreads();
  short* dst = XTb + (size_t)outer * DD * DD;
  for (int r = ty; r < 32; r += 8)
    dst[(size_t)(q0 + r) * DD + p0 + tx] = rne_bf16(tile[tx][r]);
}

// PTTb[outer][n][q] = PT[outer][q][n], PT is 192x200, out 200x192, bf16
__global__ void transpose_pt(const float* __restrict__ PT, short* __restrict__ PTTb) {
  __shared__ float tile[32][33];
  int outer = blockIdx.z;
  int q0 = blockIdx.x * 32, n0 = blockIdx.y * 32;
  int tx = threadIdx.x, ty = threadIdx.y;
  const float* src = PT + (size_t)outer * DD * OWW;
  for (int r = ty; r < 32; r += 8)
    tile[r][tx] = (n0 + tx < OWW) ? src[(size_t)(q0 + r) * OWW + n0 + tx] : 0.f;
  __syncthreads();
  short* dst = PTTb + (size_t)outer * OWW * DD;
  for (int r = ty; r < 32; r += 8)
    if (n0 + r < OWW) dst[(size_t)(n0 + r) * DD + q0 + tx] = rne_bf16(tile[tx][r]);
}

// ---------------- stage A ----------------
// y[b,i] = sum_j R[i,j] @ x[b,j] @ R[i,j]^T, split over jg halves.
// mm1: T^T[q][m] = sum_p XT[q][p] R[m][p]   (A = XT rows, B = R rows)
//      -> pack T row-major [m][q] via s4v (C gives T[m][q0..q0+3] per lane)
// mm2: y[m][n]   = sum_q T[m][q] R[n][q]    (A = T rows, B = R rows)
//      -> C-layout per lane = y[m0..m0+3][n] = y^T[n][m0..3] -> pack y^T contiguously
// Output: ypart holds y^T (192x192 row-major [n][m]) per (jg,b,i) — fused B wants y^T rows.
__global__ __launch_bounds__(512, 2) void stageA(const short* __restrict__ Rb,
                                                 const short* __restrict__ XTb,
                                                 short* __restrict__ ypart) {
  __shared__ __align__(16) short ldsR[DD * LDP];
  __shared__ __align__(16) short lds2[DD * LDP];
  const int tid = threadIdx.x;
  const int bx = blockIdx.x;
  const int b = bx >> 5, i = (bx >> 1) & 15, jg = bx & 1;
  const int lane15 = tid & 15, quad = (tid & 63) >> 4;
  const int wid = tid >> 6;
  const int wm = wid & 3;   // 0..3 -> 3 tiles each (B-operand dim)
  const int wq = wid >> 2;  // 0..1 -> 6 tiles each (A-operand dim)

  f32x4 acc_y[6][3];
  #pragma unroll
  for (int a = 0; a < 6; ++a)
    #pragma unroll
    for (int c = 0; c < 3; ++c) acc_y[a][c] = (f32x4){0.f, 0.f, 0.f, 0.f};

  for (int jj = 0; jj < 8; ++jj) {
    const int j = jg * 8 + jj;
    __syncthreads();  // previous iter done reading ldsR/lds2
    {
      const short* srcR = Rb + (size_t)(i * CC + j) * (DD * DD);
      const short* srcX = XTb + (size_t)(b * CC + j) * (DD * DD);
      for (int c = tid; c < DD * CH; c += 512) {
        int row = c / CH, col = c % CH;
        *(s8v*)(&ldsR[row * LDP + col * 8]) = *(const s8v*)(srcR + (size_t)c * 8);
        *(s8v*)(&lds2[row * LDP + col * 8]) = *(const s8v*)(srcX + (size_t)c * 8);
      }
    }
    __syncthreads();

    // mm1: T^T  (A = XT rows -> wq covers 6 q-tiles; B = R rows -> wm covers 3 m-tiles)
    f32x4 acc_t[6][3];
    #pragma unroll
    for (int a = 0; a < 6; ++a)
      #pragma unroll
      for (int c = 0; c < 3; ++c) acc_t[a][c] = (f32x4){0.f, 0.f, 0.f, 0.f};

    #pragma unroll
    for (int kc = 0; kc < 6; ++kc) {
      s8v af[6], bf[3];
      #pragma unroll
      for (int a = 0; a < 6; ++a)
        af[a] = *(const s8v*)(&lds2[((wq * 6 + a) * 16 + lane15) * LDP + kc * 32 + quad * 8]);
      #pragma unroll
      for (int c = 0; c < 3; ++c)
        bf[c] = *(const s8v*)(&ldsR[((wm * 3 + c) * 16 + lane15) * LDP + kc * 32 + quad * 8]);
      #pragma unroll
      for (int a = 0; a < 6; ++a)
        #pragma unroll
        for (int c = 0; c < 3; ++c)
          acc_t[a][c] = __builtin_amdgcn_mfma_f32_16x16x32_bf16(af[a], bf[c], acc_t[a][c], 0, 0, 0);
    }
    __syncthreads();  // done reading XT in lds2; overwrite with T

    // pack T[m][q] (bf16) into lds2
    #pragma unroll
    for (int a = 0; a < 6; ++a) {
      #pragma unroll
      for (int c = 0; c < 3; ++c) {
        s4v pk;
        #pragma unroll
        for (int r = 0; r < 4; ++r) pk[r] = rne_bf16(acc_t[a][c][r]);
        int m = (wm * 3 + c) * 16 + lane15;
        int q0 = (wq * 6 + a) * 16 + quad * 4;
        *(s4v*)(&lds2[m * LDP + q0]) = pk;
      }
    }
    __syncthreads();

    // mm2: y[m][n] += T rows x R rows  (A = T -> wq covers 6 m-tiles; B = R -> wm covers 3 n-tiles)
    #pragma unroll
    for (int kc = 0; kc < 6; ++kc) {
      s8v af[6], bf[3];
      #pragma unroll
      for (int a = 0; a < 6; ++a)
        af[a] = *(const s8v*)(&lds2[((wq * 6 + a) * 16 + lane15) * LDP + kc * 32 + quad * 8]);
      #pragma unroll
      for (int c = 0; c < 3; ++c)
        bf[c] = *(const s8v*)(&ldsR[((wm * 3 + c) * 16 + lane15) * LDP + kc * 32 + quad * 8]);
      #pragma unroll
      for (int a = 0; a < 6; ++a)
        #pragma unroll
        for (int c = 0; c < 3; ++c)
          acc_y[a][c] = __builtin_amdgcn_mfma_f32_16x16x32_bf16(af[a], bf[c], acc_y[a][c], 0, 0, 0);
    }
  }

  // pack y^T [n][m] into lds2, then coalesced store
  __syncthreads();
  #pragma unroll
  for (int a = 0; a < 6; ++a) {
    #pragma unroll
    for (int c = 0; c < 3; ++c) {
      s4v pk;
      #pragma unroll
      for (int r = 0; r < 4; ++r) pk[r] = rne_bf16(acc_y[a][c][r]);
      int n = (wm * 3 + c) * 16 + lane15;       // B-row = n (col of y)
      int m0 = (wq * 6 + a) * 16 + quad * 4;    // A-row = m, 4 consecutive
      *(s4v*)(&lds2[n * LDP + m0]) = pk;
    }
  }
  __syncthreads();
  {
    short* dst = ypart + (size_t)(jg * (BB * CC) + b * CC + i) * (DD * DD);
    for (int c = tid; c < DD * CH; c += 512) {
      int row = c / CH, col = c % CH;
      *(s8v*)(dst + (size_t)c * 8) = *(const s8v*)(&lds2[row * LDP + col * 8]);
    }
  }
}

// ---------------- sum_y: ysum = part0 + part1 (bf16) ----------------
__global__ void sum_y(const short* __restrict__ ypart, short* __restrict__ ysum, int n8) {
  int idx = blockIdx.x * 256 + threadIdx.x;
  if (idx >= n8) return;
  s8v v0 = *(const s8v*)(ypart + (size_t)idx * 8);
  s8v v1 = *(const s8v*)(ypart + (size_t)(BB * CC) * (DD * DD) + (size_t)idx * 8);
  s8v o;
  #pragma unroll
  for (int r = 0; r < 8; ++r) o[r] = rne_bf16(bf2f(v0[r]) + bf2f(v1[r]));
  *(s8v*)(ysum + (size_t)idx * 8) = o;
}

// ---------------- fused stage B ----------------
// out[b,oc] = sum_j P[oc,j] @ y[b,j] @ PT[oc,j]
// Block = (b, oc, nh, jg): 4 j's per block, n-half of 100 cols, out acc in registers.
// Per j:  mm_b1: U^T[q][m] = sum_p yT[q][p] P[m][p]   (A = yT rows, B = P rows)
//         pack U[m][q] into yT rows 0..63 (yT consumed)
//         mm_b2: out[m][n] += sum_q U[m][q] PTT[n][q] (A = U rows, B = PT^T rows)
// Writes fp32 partial per jg; reduce_out sums the 4 partials.
#define PROWS 64
#define PTROWS 128
__global__ __launch_bounds__(512, 2) void fusedB(const short* __restrict__ ysum,
                                                 const short* __restrict__ Pb,
                                                 const short* __restrict__ PTTb,
                                                 float* __restrict__ partials) {
  __shared__ __align__(16) short ldsYT[DD * LDP];     // 76.8 KB; rows 0..63 reused for U
  __shared__ __align__(16) short ldsP[PROWS * LDP];   // 25.6 KB
  __shared__ __align__(16) short ldsPT[PTROWS * LDP]; // 51.2 KB
  const int tid = threadIdx.x;
  const int bx = blockIdx.x;
  const int jg = bx & 3, nh = (bx >> 2) & 1, oc = (bx >> 3) & 3, b = bx >> 5;
  const int lane15 = tid & 15, quad = (tid & 63) >> 4;
  const int wid = tid >> 6;
  // mm_b1 wave grid: 4 (q) x 2 (m)
  const int wq1 = wid >> 1, wm1 = wid & 1;
  // mm_b2 wave grid: 2 (m) x 4 (n)
  const int wm2 = wid & 1, wn2 = wid >> 1;

  f32x4 acc_o[2][2];
  #pragma unroll
  for (int a = 0; a < 2; ++a)
    #pragma unroll
    for (int e = 0; e < 2; ++e) acc_o[a][e] = (f32x4){0.f, 0.f, 0.f, 0.f};

  const s8v z = {0, 0, 0, 0, 0, 0, 0, 0};
  for (int jj = 0; jj < 4; ++jj) {
    const int j = jg * 4 + jj;
    __syncthreads();  // prev iter done reading U/ldsP/ldsPT
    {
      const short* sy = ysum + (size_t)(b * CC + j) * (DD * DD);
      for (int c = tid; c < DD * CH; c += 512) {
        int row = c / CH, col = c % CH;
        *(s8v*)(&ldsYT[row * LDP + col * 8]) = *(const s8v*)(sy + (size_t)c * 8);
      }
      const short* sp = Pb + (size_t)(oc * CC + j) * (OHH * DD);
      for (int c = tid; c < PROWS * CH; c += 512) {
        int row = c / CH, col = c % CH;
        *(s8v*)(&ldsP[row * LDP + col * 8]) =
            (c < OHH * CH) ? *(const s8v*)(sp + (size_t)c * 8) : z;
      }
      const short* st = PTTb + (size_t)(oc * CC + j) * (OWW * DD) + (size_t)nh * 100 * DD;
      for (int c = tid; c < PTROWS * CH; c += 512) {
        int row = c / CH, col = c % CH;
        *(s8v*)(&ldsPT[row * LDP + col * 8]) =
            (c < 100 * CH) ? *(const s8v*)(st + (size_t)c * 8) : z;
      }
    }
    __syncthreads();

    // mm_b1: U^T[q][m]; wq1 -> 3 q-tiles, wm1 -> 2 m-tiles
    f32x4 acc_t[3][2];
    #pragma unroll
    for (int a = 0; a < 3; ++a)
      #pragma unroll
      for (int c = 0; c < 2; ++c) acc_t[a][c] = (f32x4){0.f, 0.f, 0.f, 0.f};
    #pragma unroll
    for (int kc = 0; kc < 6; ++kc) {
      s8v af[3], bf[2];
      #pragma unroll
      for (int a = 0; a < 3; ++a)
        af[a] = *(const s8v*)(&ldsYT[((wq1 * 3 + a) * 16 + lane15) * LDP + kc * 32 + quad * 8]);
      #pragma unroll
      for (int c = 0; c < 2; ++c)
        bf[c] = *(const s8v*)(&ldsP[((wm1 * 2 + c) * 16 + lane15) * LDP + kc * 32 + quad * 8]);
      #pragma unroll
      for (int a = 0; a < 3; ++a)
        #pragma unroll
        for (int c = 0; c < 2; ++c)
          acc_t[a][c] = __builtin_amdgcn_mfma_f32_16x16x32_bf16(af[a], bf[c], acc_t[a][c], 0, 0, 0);
    }
    __syncthreads();  // yT fully consumed

    // pack U[m][q] into ldsYT rows 0..63
    #pragma unroll
    for (int a = 0; a < 3; ++a) {
      #pragma unroll
      for (int c = 0; c < 2; ++c) {
        s4v pk;
        #pragma unroll
        for (int r = 0; r < 4; ++r) pk[r] = rne_bf16(acc_t[a][c][r]);
        int m = (wm1 * 2 + c) * 16 + lane15;
        int q0 = (wq1 * 3 + a) * 16 + quad * 4;
        *(s4v*)(&ldsYT[m * LDP + q0]) = pk;
      }
    }
    __syncthreads();

    // mm_b2: out[m][n] += U rows x PT^T rows; wm2 -> 2 m-tiles, wn2 -> 2 n-tiles
    #pragma unroll
    for (int kc = 0; kc < 6; ++kc) {
      s8v af[2], bf[2];
      #pragma unroll
      for (int a = 0; a < 2; ++a)
        af[a] = *(const s8v*)(&ldsYT[((wm2 * 2 + a) * 16 + lane15) * LDP + kc * 32 + quad * 8]);
      #pragma unroll
      for (int e = 0; e < 2; ++e)
        bf[e] = *(const s8v*)(&ldsPT[((wn2 * 2 + e) * 16 + lane15) * LDP + kc * 32 + quad * 8]);
      #pragma unroll
      for (int a = 0; a < 2; ++a)
        #pragma unroll
        for (int e = 0; e < 2; ++e)
          acc_o[a][e] = __builtin_amdgcn_mfma_f32_16x16x32_bf16(af[a], bf[e], acc_o[a][e], 0, 0, 0);
    }
  }

  // store fp32 partial: partials[jg][b*OCC+oc][m][nh*100 + n]
  float* dst = partials + ((size_t)jg * (BB * OCC) + b * OCC + oc) * (OHH * OWW);
  #pragma unroll
  for (int a = 0; a < 2; ++a) {
    #pragma unroll
    for (int e = 0; e < 2; ++e) {
      int n = (wn2 * 2 + e) * 16 + lane15;
      if (n < 100) {
        #pragma unroll
        for (int r = 0; r < 4; ++r) {
          int m = (wm2 * 2 + a) * 16 + quad * 4 + r;
          if (m < OHH)
            dst[(size_t)m * OWW + nh * 100 + n] = acc_o[a][e][r];
        }
      }
    }
  }
}

// ---------------- reduce: out = sum of 4 jg partials ----------------
__global__ void reduce_out(const float* __restrict__ partials, float* __restrict__ out, int n4) {
  int idx = blockIdx.x * 256 + threadIdx.x;
  if (idx >= n4) return;
  const size_t stride = (size_t)(BB * OCC) * OHH * OWW;
  f4v s = *(const f4v*)(partials + (size_t)idx * 4);
  #pragma unroll
  for (int g = 1; g < 4; ++g) {
    f4v v = *(const f4v*)(partials + g * stride + (size_t)idx * 4);
    #pragma unroll
    for (int r = 0; r < 4; ++r) s[r] += v[r];
  }
  *(f4v*)(out + (size_t)idx * 4) = s;
}

// ---------------- launcher ----------------

extern "C" void kernel_launch(void* const* d_in, const int* in_sizes, int n_in,
                              void* d_out, int out_size, void* d_ws, size_t ws_size,
                              hipStream_t stream) {
  const float* x  = (const float*)d_in[0];
  const float* R  = (const float*)d_in[1];
  const float* P  = (const float*)d_in[2];
  const float* PT = (const float*)d_in[3];
  float* out = (float*)d_out;

  short* W = (short*)d_ws;
  const size_t nR   = (size_t)CC * CC * DD * DD;     // 9,437,184
  const size_t nX   = (size_t)BB * CC * DD * DD;     // 4,718,592
  const size_t nP   = (size_t)OCC * CC * OHH * DD;   // 614,400
  const size_t nPT  = (size_t)OCC * CC * OWW * DD;   // 2,457,600
  const size_t nYP  = 2 * nX;
  short* Rb    = W;
  short* XTb   = Rb + nR;
  short* Pb    = XTb + nX;
  short* PTTb  = Pb + nP;
  short* ypart = PTTb + nPT;
  short* ysum  = ypart + nYP;
  float* parts = (float*)(ysum + nX);   // 4 * 32 * 50 * 200 fp32 = 5.12 MB

  cvt_bf16<<<(int)(nR / 4 / 256), 256, 0, stream>>>(R, Rb, (int)(nR / 4));
  cvt_bf16<<<(int)(nP / 4 / 256), 256, 0, stream>>>(P, Pb, (int)(nP / 4));
  transpose_x<<<dim3(6, 6, BB * CC), dim3(32, 8), 0, stream>>>(x, XTb);
  transpose_pt<<<dim3(6, 7, OCC * CC), dim3(32, 8), 0, stream>>>(PT, PTTb);

  stageA<<<BB * CC * 2, 512, 0, stream>>>(Rb, XTb, ypart);
  sum_y<<<(int)(nX / 8 / 256), 256, 0, stream>>>(ypart, ysum, (int)(nX / 8));
  fusedB<<<BB * OCC * 2 * 4, 512, 0, stream>>>(ysum, Pb, PTTb, parts);

  const int n4 = BB * OCC * OHH * OWW / 4;  // 80,000
  reduce_out<<<(n4 + 255) / 256, 256, 0, stream>>>(parts, out, n4);
}